// Round 1
// baseline (3975.605 us; speedup 1.0000x reference)
//
#include <hip/hip_runtime.h>
#include <hip/hip_bf16.h>
#include <math.h>

typedef unsigned short u16;
typedef unsigned int u32;
typedef short s16x8 __attribute__((ext_vector_type(8)));
typedef float f32x4 __attribute__((ext_vector_type(4)));

#define SEQL 2048
#define NL 4
#define MROWS 8192   /* BATCH*SEQL */

// ---------- bf16 helpers (RNE) ----------
static __device__ __forceinline__ u16 f2b(float f) {
  union { float f; u32 u; } v; v.f = f;
  u32 u = v.u;
  return (u16)((u + 0x7FFFu + ((u >> 16) & 1u)) >> 16);
}
static __device__ __forceinline__ float b2f(u16 h) {
  union { u32 u; float f; } v; v.u = ((u32)h) << 16; return v.f;
}

// ---------- async global->LDS (16B per lane) ----------
static __device__ __forceinline__ void gld16(const void* g, void* l) {
  __builtin_amdgcn_global_load_lds(
      (const __attribute__((address_space(1))) u32*)g,
      (__attribute__((address_space(3))) u32*)l, 16, 0, 0);
}

// ---------- GEMM: C(M,N) = A(M,K) @ W(N,K)^T, bf16 in, fp32 acc ----------
enum { EPI_BF16 = 0, EPI_F32 = 1, EPI_SOFTPLUS = 2, EPI_ADDF32 = 3, EPI_BIASRELU = 4, EPI_ADDBIAS = 5 };

template <int EPI>
__global__ void __launch_bounds__(256)
gemm_bt(const u16* __restrict__ A, const u16* __restrict__ W,
        int K, int N,
        float* __restrict__ outF, u16* __restrict__ outB,
        const float* __restrict__ bias)
{
  __shared__ u16 sA[128 * 32];
  __shared__ u16 sB[128 * 32];
  const int tid = threadIdx.x;
  const int wid = tid >> 6, lane = tid & 63;
  const int bm = blockIdx.y, bn = blockIdx.x;
  const int wm = (wid >> 1) * 64, wn = (wid & 1) * 64;
  f32x4 acc[4][4] = {};

  // staging: each wave stages 2 chunks of 1KB for A and for B.
  const int chunk = wid * 2;
  const int r0 = lane >> 2;            // row within 16-row chunk
  const int kq = (lane & 3) * 8;       // bf16 elems into the 32-wide k slab
  const u16* gA0 = A + (size_t)(bm * 128 + chunk * 16 + r0) * K + kq;
  const u16* gA1 = A + (size_t)(bm * 128 + (chunk + 1) * 16 + r0) * K + kq;
  const u16* gB0 = W + (size_t)(bn * 128 + chunk * 16 + r0) * K + kq;
  const u16* gB1 = W + (size_t)(bn * 128 + (chunk + 1) * 16 + r0) * K + kq;
  u16* lA0 = sA + chunk * 512;         // wave-uniform LDS bases (1KB chunks)
  u16* lA1 = sA + (chunk + 1) * 512;
  u16* lB0 = sB + chunk * 512;
  u16* lB1 = sB + (chunk + 1) * 512;

  const int mrow = lane & 15;
  const int ko = (lane >> 4) * 8;

  for (int kt = 0; kt < K; kt += 32) {
    gld16(gA0 + kt, lA0);
    gld16(gA1 + kt, lA1);
    gld16(gB0 + kt, lB0);
    gld16(gB1 + kt, lB1);
    __syncthreads();   // drains vmcnt (global_load_lds) per compiler barrier semantics
    s16x8 af[4], bf[4];
#pragma unroll
    for (int i = 0; i < 4; ++i)
      af[i] = *(const s16x8*)(sA + (wm + i * 16 + mrow) * 32 + ko);
#pragma unroll
    for (int i = 0; i < 4; ++i)
      bf[i] = *(const s16x8*)(sB + (wn + i * 16 + mrow) * 32 + ko);
#pragma unroll
    for (int mi = 0; mi < 4; ++mi)
#pragma unroll
      for (int ni = 0; ni < 4; ++ni)
        acc[mi][ni] = __builtin_amdgcn_mfma_f32_16x16x32_bf16(af[mi], bf[ni], acc[mi][ni], 0, 0, 0);
    __syncthreads();
  }

  const int m0 = bm * 128 + wm + (lane >> 4) * 4;
  const int n0 = bn * 128 + wn + (lane & 15);
#pragma unroll
  for (int mi = 0; mi < 4; ++mi) {
#pragma unroll
    for (int ni = 0; ni < 4; ++ni) {
#pragma unroll
      for (int r = 0; r < 4; ++r) {
        const int m = m0 + mi * 16 + r;
        const int n = n0 + ni * 16;
        const float v = acc[mi][ni][r];
        const size_t off = (size_t)m * N + n;
        if (EPI == EPI_BF16) {
          outB[off] = f2b(v);
        } else if (EPI == EPI_F32) {
          outF[off] = v;
        } else if (EPI == EPI_SOFTPLUS) {
          float t = v + bias[n];
          float sp = (t > 20.f) ? t : log1pf(expf(t));
          outB[off] = f2b(sp);
        } else if (EPI == EPI_ADDF32) {
          outF[off] += v;
        } else if (EPI == EPI_BIASRELU) {
          float t = v + bias[n];
          outB[off] = f2b(t > 0.f ? t : 0.f);
        } else if (EPI == EPI_ADDBIAS) {
          outF[off] += v + bias[n];
        }
      }
    }
  }
}

// ---------- embedding ----------
__global__ void __launch_bounds__(256)
embed_kernel(const int* __restrict__ x, const float* __restrict__ tok,
             const float* __restrict__ pos, float* __restrict__ h)
{
  const int row = blockIdx.x;
  const int l = row & (SEQL - 1);
  const int ix = x[row];
  const float* t = tok + (size_t)ix * 768;
  const float* p = pos + (size_t)l * 768;
  float* o = h + (size_t)row * 768;
  for (int c = threadIdx.x; c < 768; c += 256)
    o[c] = t[c] + p[c];
}

// ---------- layernorm (fp32 in -> bf16 out) ----------
__global__ void __launch_bounds__(256)
ln_kernel(const float* __restrict__ h, const float* __restrict__ g,
          const float* __restrict__ b, u16* __restrict__ out)
{
  __shared__ float red[8];
  const int row = blockIdx.x, tid = threadIdx.x;
  const float* hr = h + (size_t)row * 768;
  const float v0 = hr[tid], v1 = hr[tid + 256], v2 = hr[tid + 512];
  float s = v0 + v1 + v2;
  float q = v0 * v0 + v1 * v1 + v2 * v2;
  for (int off = 32; off; off >>= 1) {
    s += __shfl_down(s, off);
    q += __shfl_down(q, off);
  }
  if ((tid & 63) == 0) { red[(tid >> 6) * 2] = s; red[(tid >> 6) * 2 + 1] = q; }
  __syncthreads();
  const float S = red[0] + red[2] + red[4] + red[6];
  const float Q = red[1] + red[3] + red[5] + red[7];
  const float mu = S * (1.f / 768.f);
  const float var = Q * (1.f / 768.f) - mu * mu;
  const float rs = rsqrtf(var + 1e-5f);
  u16* o = out + (size_t)row * 768;
  o[tid]       = f2b((v0 - mu) * rs * g[tid]       + b[tid]);
  o[tid + 256] = f2b((v1 - mu) * rs * g[tid + 256] + b[tid + 256]);
  o[tid + 512] = f2b((v2 - mu) * rs * g[tid + 512] + b[tid + 512]);
}

// ---------- causal depthwise conv (width 4) + silu ----------
__global__ void __launch_bounds__(256)
conv_kernel(const u16* __restrict__ xz, const float* __restrict__ cw,
            const float* __restrict__ cb, u16* __restrict__ xc)
{
  const int d = blockIdx.x * 256 + threadIdx.x;   // 0..1535
  const int bl = blockIdx.y;                      // 0..8191
  const int l = bl & (SEQL - 1);
  const float w0 = cw[d * 4 + 0], w1 = cw[d * 4 + 1], w2 = cw[d * 4 + 2], w3 = cw[d * 4 + 3];
  const u16* xp = xz + (size_t)bl * 3072 + d;
  float acc = cb[d];
  acc += w3 * b2f(xp[0]);
  if (l >= 1) acc += w2 * b2f(xp[-3072]);
  if (l >= 2) acc += w1 * b2f(xp[-2 * 3072]);
  if (l >= 3) acc += w0 * b2f(xp[-3 * 3072]);
  const float sv = acc / (1.f + __expf(-acc));
  xc[(size_t)bl * 1536 + d] = f2b(sv);
}

// ---------- dtr extraction (proj fp32 -> bf16, pad 48->64) ----------
__global__ void __launch_bounds__(64)
dtr_kernel(const float* __restrict__ proj, u16* __restrict__ dtr)
{
  const int row = blockIdx.x, c = threadIdx.x;   // block=64
  const float v = (c < 48) ? proj[(size_t)row * 128 + c] : 0.f;
  dtr[(size_t)row * 64 + c] = f2b(v);
}

// ---------- selective scan (fused +x*D and *silu(z)) ----------
__global__ void __launch_bounds__(256)
scan_kernel(const u16* __restrict__ xc, const u16* __restrict__ dt,
            const float* __restrict__ proj, const u16* __restrict__ xz,
            const float* __restrict__ Alog, const float* __restrict__ Dp,
            u16* __restrict__ ys)
{
  __shared__ u16 s_dt[64][16], s_x[64][16], s_z[64][16];
  __shared__ float s_B[64][16], s_C[64][16];
  const int b = blockIdx.y;         // batch
  const int d0 = blockIdx.x * 16;   // channel chunk
  const int tid = threadIdx.x;
  const int s = tid & 15, dl = tid >> 4;
  const int d = d0 + dl;
  const float Av = -expf(Alog[d * 16 + s]);
  const float Dv = Dp[d];
  float h = 0.f;
  const int jj = tid >> 2, q = tid & 3;
  const size_t rowbase = (size_t)b * SEQL;

  for (int l0 = 0; l0 < SEQL; l0 += 64) {
    const size_t r = rowbase + l0 + jj;
    *(ushort4*)&s_dt[jj][q * 4] = *(const ushort4*)(dt + r * 1536 + d0 + q * 4);
    *(ushort4*)&s_x[jj][q * 4]  = *(const ushort4*)(xc + r * 1536 + d0 + q * 4);
    *(ushort4*)&s_z[jj][q * 4]  = *(const ushort4*)(xz + r * 3072 + 1536 + d0 + q * 4);
    *(float4*)&s_B[jj][q * 4]   = *(const float4*)(proj + r * 128 + 48 + q * 4);
    *(float4*)&s_C[jj][q * 4]   = *(const float4*)(proj + r * 128 + 64 + q * 4);
    __syncthreads();
    for (int j = 0; j < 64; ++j) {
      const float dtv = b2f(s_dt[j][dl]);
      const float xv  = b2f(s_x[j][dl]);
      const float Bv  = s_B[j][s];
      const float Cv  = s_C[j][s];
      const float e = __expf(dtv * Av);
      h = e * h + (dtv * xv) * Bv;
      float p = h * Cv;
      p += __shfl_xor(p, 1);
      p += __shfl_xor(p, 2);
      p += __shfl_xor(p, 4);
      p += __shfl_xor(p, 8);
      if (s == 0) {
        float y = p + xv * Dv;
        const float zv = b2f(s_z[j][dl]);
        y *= zv / (1.f + __expf(-zv));
        ys[(rowbase + l0 + j) * 1536 + d] = f2b(y);
      }
    }
    __syncthreads();
  }
}

// ---------- weight conversion ----------
__global__ void __launch_bounds__(256)
cvt_kernel(const float* __restrict__ src, u16* __restrict__ dst, int n)
{
  const int i = blockIdx.x * 256 + threadIdx.x;
  if (i < n) dst[i] = f2b(src[i]);
}
__global__ void __launch_bounds__(256)
cvt_pad_xproj(const float* __restrict__ src, u16* __restrict__ dst)
{
  // src [80][1536] -> dst [128][1536] (rows >=80 zero)
  const int c = blockIdx.x * 256 + threadIdx.x;
  const int r = blockIdx.y;
  dst[(size_t)r * 1536 + c] = (r < 80) ? f2b(src[(size_t)r * 1536 + c]) : (u16)0;
}
__global__ void __launch_bounds__(64)
cvt_pad_dtp(const float* __restrict__ src, u16* __restrict__ dst)
{
  // src [1536][48] -> dst [1536][64] (cols >=48 zero)
  const int c = threadIdx.x, r = blockIdx.x;
  dst[(size_t)r * 64 + c] = (c < 48) ? f2b(src[(size_t)r * 48 + c]) : (u16)0;
}

extern "C" void kernel_launch(void* const* d_in, const int* in_sizes, int n_in,
                              void* d_out, int out_size, void* d_ws, size_t ws_size,
                              hipStream_t stream)
{
  (void)in_sizes; (void)n_in; (void)out_size; (void)ws_size;
  const int*   x      = (const int*)d_in[0];
  const float* tok    = (const float*)d_in[1];
  const float* pos    = (const float*)d_in[2];
  const float* ln1g   = (const float*)d_in[3];
  const float* ln1b   = (const float*)d_in[4];
  const float* in_w   = (const float*)d_in[5];
  const float* conv_w = (const float*)d_in[6];
  const float* conv_b = (const float*)d_in[7];
  const float* xprojw = (const float*)d_in[8];
  const float* dtpw   = (const float*)d_in[9];
  const float* dtpb   = (const float*)d_in[10];
  const float* Alog   = (const float*)d_in[11];
  const float* Dp     = (const float*)d_in[12];
  const float* out_w  = (const float*)d_in[13];
  const float* ln2g   = (const float*)d_in[14];
  const float* ln2b   = (const float*)d_in[15];
  const float* w1     = (const float*)d_in[16];
  const float* b1     = (const float*)d_in[17];
  const float* w2     = (const float*)d_in[18];
  const float* b2     = (const float*)d_in[19];
  float* h = (float*)d_out;

  char* ws = (char*)d_ws;
  size_t off = 0;
  auto alloc = [&](size_t bytes) -> void* {
    void* p = ws + off;
    off += (bytes + 255) & ~(size_t)255;
    return p;
  };
  u16* wbIn  = (u16*)alloc((size_t)NL * 3072 * 768 * 2);
  u16* wbOut = (u16*)alloc((size_t)NL * 768 * 1536 * 2);
  u16* wbW1  = (u16*)alloc((size_t)NL * 3072 * 768 * 2);
  u16* wbW2  = (u16*)alloc((size_t)NL * 768 * 3072 * 2);
  u16* wbXp  = (u16*)alloc((size_t)NL * 128 * 1536 * 2);
  u16* wbDtp = (u16*)alloc((size_t)NL * 1536 * 64 * 2);
  u16* aBf   = (u16*)alloc((size_t)MROWS * 768 * 2);
  u16* xzBf  = (u16*)alloc((size_t)MROWS * 3072 * 2);
  u16* xcBf  = (u16*)alloc((size_t)MROWS * 1536 * 2);
  float* projF = (float*)alloc((size_t)MROWS * 128 * 4);
  u16* dtrBf = (u16*)alloc((size_t)MROWS * 64 * 2);
  u16* dtBf  = (u16*)alloc((size_t)MROWS * 1536 * 2);
  u16* ysBf  = (u16*)alloc((size_t)MROWS * 1536 * 2);
  u16* f1Bf  = xzBf;  // alias: z consumed by scan before MLP writes f1

  // convert weights to bf16 (every call; deterministic)
  { int n = NL * 3072 * 768; cvt_kernel<<<(n + 255) / 256, 256, 0, stream>>>(in_w, wbIn, n); }
  { int n = NL * 768 * 1536; cvt_kernel<<<(n + 255) / 256, 256, 0, stream>>>(out_w, wbOut, n); }
  { int n = NL * 3072 * 768; cvt_kernel<<<(n + 255) / 256, 256, 0, stream>>>(w1, wbW1, n); }
  { int n = NL * 768 * 3072; cvt_kernel<<<(n + 255) / 256, 256, 0, stream>>>(w2, wbW2, n); }
  for (int i = 0; i < NL; ++i) {
    cvt_pad_xproj<<<dim3(6, 128), 256, 0, stream>>>(xprojw + (size_t)i * 80 * 1536,
                                                    wbXp + (size_t)i * 128 * 1536);
    cvt_pad_dtp<<<1536, 64, 0, stream>>>(dtpw + (size_t)i * 1536 * 48,
                                         wbDtp + (size_t)i * 1536 * 64);
  }

  embed_kernel<<<MROWS, 256, 0, stream>>>(x, tok, pos, h);

  for (int i = 0; i < NL; ++i) {
    ln_kernel<<<MROWS, 256, 0, stream>>>(h, ln1g + i * 768, ln1b + i * 768, aBf);
    gemm_bt<EPI_BF16><<<dim3(24, 64), 256, 0, stream>>>(
        aBf, wbIn + (size_t)i * 3072 * 768, 768, 3072, nullptr, xzBf, nullptr);
    conv_kernel<<<dim3(6, MROWS), 256, 0, stream>>>(
        xzBf, conv_w + (size_t)i * 1536 * 4, conv_b + (size_t)i * 1536, xcBf);
    gemm_bt<EPI_F32><<<dim3(1, 64), 256, 0, stream>>>(
        xcBf, wbXp + (size_t)i * 128 * 1536, 1536, 128, projF, nullptr, nullptr);
    dtr_kernel<<<MROWS, 64, 0, stream>>>(projF, dtrBf);
    gemm_bt<EPI_SOFTPLUS><<<dim3(12, 64), 256, 0, stream>>>(
        dtrBf, wbDtp + (size_t)i * 1536 * 64, 64, 1536, nullptr, dtBf, dtpb + i * 1536);
    scan_kernel<<<dim3(96, 4), 256, 0, stream>>>(
        xcBf, dtBf, projF, xzBf, Alog + (size_t)i * 1536 * 16, Dp + i * 1536, ysBf);
    gemm_bt<EPI_ADDF32><<<dim3(6, 64), 256, 0, stream>>>(
        ysBf, wbOut + (size_t)i * 768 * 1536, 1536, 768, h, nullptr, nullptr);
    ln_kernel<<<MROWS, 256, 0, stream>>>(h, ln2g + i * 768, ln2b + i * 768, aBf);
    gemm_bt<EPI_BIASRELU><<<dim3(24, 64), 256, 0, stream>>>(
        aBf, wbW1 + (size_t)i * 3072 * 768, 768, 3072, nullptr, f1Bf, b1 + i * 3072);
    gemm_bt<EPI_ADDBIAS><<<dim3(6, 64), 256, 0, stream>>>(
        f1Bf, wbW2 + (size_t)i * 768 * 3072, 3072, 768, h, nullptr, b2 + i * 768);
  }
}

// Round 2
// 2434.291 us; speedup vs baseline: 1.6332x; 1.6332x over previous
//
#include <hip/hip_runtime.h>
#include <hip/hip_bf16.h>
#include <math.h>

typedef unsigned short u16;
typedef unsigned int u32;
typedef short s16x8 __attribute__((ext_vector_type(8)));
typedef float f32x4 __attribute__((ext_vector_type(4)));

#define SEQL 2048
#define NL 4
#define MROWS 8192   /* BATCH*SEQL */
#define NC 32        /* scan chunks */
#define TCH 64       /* steps per chunk (NC*TCH == SEQL) */

// ---------- bf16 helpers (RNE) ----------
static __device__ __forceinline__ u16 f2b(float f) {
  union { float f; u32 u; } v; v.f = f;
  u32 u = v.u;
  return (u16)((u + 0x7FFFu + ((u >> 16) & 1u)) >> 16);
}
static __device__ __forceinline__ float b2f(u16 h) {
  union { u32 u; float f; } v; v.u = ((u32)h) << 16; return v.f;
}

// ---------- async global->LDS (16B per lane) ----------
static __device__ __forceinline__ void gld16(const void* g, void* l) {
  __builtin_amdgcn_global_load_lds(
      (const __attribute__((address_space(1))) u32*)g,
      (__attribute__((address_space(3))) u32*)l, 16, 0, 0);
}

// ---------- GEMM: C(M,N) = A(M,K) @ W(N,K)^T, bf16 in, fp32 acc ----------
enum { EPI_BF16 = 0, EPI_PROJ = 1, EPI_SOFTPLUS = 2, EPI_ADDF32 = 3, EPI_BIASRELU = 4, EPI_ADDBIAS = 5 };

template <int EPI>
__global__ void __launch_bounds__(256)
gemm_bt(const u16* __restrict__ A, const u16* __restrict__ W,
        int K, int N,
        float* __restrict__ outF, u16* __restrict__ outB,
        const float* __restrict__ bias)
{
  __shared__ u16 sA[128 * 32];
  __shared__ u16 sB[128 * 32];
  const int tid = threadIdx.x;
  const int wid = tid >> 6, lane = tid & 63;
  const int bm = blockIdx.y, bn = blockIdx.x;
  const int wm = (wid >> 1) * 64, wn = (wid & 1) * 64;
  f32x4 acc[4][4] = {};

  // staging: each wave stages 2 chunks of 1KB for A and for B.
  const int chunk = wid * 2;
  const int r0 = lane >> 2;            // row within 16-row chunk
  const int kq = (lane & 3) * 8;       // bf16 elems into the 32-wide k slab
  const u16* gA0 = A + (size_t)(bm * 128 + chunk * 16 + r0) * K + kq;
  const u16* gA1 = A + (size_t)(bm * 128 + (chunk + 1) * 16 + r0) * K + kq;
  const u16* gB0 = W + (size_t)(bn * 128 + chunk * 16 + r0) * K + kq;
  const u16* gB1 = W + (size_t)(bn * 128 + (chunk + 1) * 16 + r0) * K + kq;
  u16* lA0 = sA + chunk * 512;         // wave-uniform LDS bases (1KB chunks)
  u16* lA1 = sA + (chunk + 1) * 512;
  u16* lB0 = sB + chunk * 512;
  u16* lB1 = sB + (chunk + 1) * 512;

  const int mrow = lane & 15;
  const int ko = (lane >> 4) * 8;

  for (int kt = 0; kt < K; kt += 32) {
    gld16(gA0 + kt, lA0);
    gld16(gA1 + kt, lA1);
    gld16(gB0 + kt, lB0);
    gld16(gB1 + kt, lB1);
    __syncthreads();   // drains vmcnt (global_load_lds) per compiler barrier semantics
    s16x8 af[4], bf[4];
#pragma unroll
    for (int i = 0; i < 4; ++i)
      af[i] = *(const s16x8*)(sA + (wm + i * 16 + mrow) * 32 + ko);
#pragma unroll
    for (int i = 0; i < 4; ++i)
      bf[i] = *(const s16x8*)(sB + (wn + i * 16 + mrow) * 32 + ko);
#pragma unroll
    for (int mi = 0; mi < 4; ++mi)
#pragma unroll
      for (int ni = 0; ni < 4; ++ni)
        acc[mi][ni] = __builtin_amdgcn_mfma_f32_16x16x32_bf16(af[mi], bf[ni], acc[mi][ni], 0, 0, 0);
    __syncthreads();
  }

  const int m0 = bm * 128 + wm + (lane >> 4) * 4;
  const int n0 = bn * 128 + wn + (lane & 15);
#pragma unroll
  for (int mi = 0; mi < 4; ++mi) {
#pragma unroll
    for (int ni = 0; ni < 4; ++ni) {
#pragma unroll
      for (int r = 0; r < 4; ++r) {
        const int m = m0 + mi * 16 + r;
        const int n = n0 + ni * 16;
        const float v = acc[mi][ni][r];
        const size_t off = (size_t)m * N + n;
        if (EPI == EPI_BF16) {
          outB[off] = f2b(v);
        } else if (EPI == EPI_PROJ) {
          outF[off] = v;                      // fp32 proj (B,C live at cols 48..79)
          if (n < 48)      outB[(size_t)m * 64 + n] = f2b(v);   // dtr, bf16, padded
          else if (n < 64) outB[(size_t)m * 64 + n] = 0;
        } else if (EPI == EPI_SOFTPLUS) {
          float t = v + bias[n];
          float sp = (t > 20.f) ? t : log1pf(expf(t));
          outB[off] = f2b(sp);
        } else if (EPI == EPI_ADDF32) {
          outF[off] += v;
        } else if (EPI == EPI_BIASRELU) {
          float t = v + bias[n];
          outB[off] = f2b(t > 0.f ? t : 0.f);
        } else if (EPI == EPI_ADDBIAS) {
          outF[off] += v + bias[n];
        }
      }
    }
  }
}

// ---------- embedding ----------
__global__ void __launch_bounds__(256)
embed_kernel(const int* __restrict__ x, const float* __restrict__ tok,
             const float* __restrict__ pos, float* __restrict__ h)
{
  const int row = blockIdx.x;
  const int l = row & (SEQL - 1);
  const int ix = x[row];
  const float* t = tok + (size_t)ix * 768;
  const float* p = pos + (size_t)l * 768;
  float* o = h + (size_t)row * 768;
  for (int c = threadIdx.x; c < 768; c += 256)
    o[c] = t[c] + p[c];
}

// ---------- layernorm (fp32 in -> bf16 out) ----------
__global__ void __launch_bounds__(256)
ln_kernel(const float* __restrict__ h, const float* __restrict__ g,
          const float* __restrict__ b, u16* __restrict__ out)
{
  __shared__ float red[8];
  const int row = blockIdx.x, tid = threadIdx.x;
  const float* hr = h + (size_t)row * 768;
  const float v0 = hr[tid], v1 = hr[tid + 256], v2 = hr[tid + 512];
  float s = v0 + v1 + v2;
  float q = v0 * v0 + v1 * v1 + v2 * v2;
  for (int off = 32; off; off >>= 1) {
    s += __shfl_down(s, off);
    q += __shfl_down(q, off);
  }
  if ((tid & 63) == 0) { red[(tid >> 6) * 2] = s; red[(tid >> 6) * 2 + 1] = q; }
  __syncthreads();
  const float S = red[0] + red[2] + red[4] + red[6];
  const float Q = red[1] + red[3] + red[5] + red[7];
  const float mu = S * (1.f / 768.f);
  const float var = Q * (1.f / 768.f) - mu * mu;
  const float rs = rsqrtf(var + 1e-5f);
  u16* o = out + (size_t)row * 768;
  o[tid]       = f2b((v0 - mu) * rs * g[tid]       + b[tid]);
  o[tid + 256] = f2b((v1 - mu) * rs * g[tid + 256] + b[tid + 256]);
  o[tid + 512] = f2b((v2 - mu) * rs * g[tid + 512] + b[tid + 512]);
}

// ---------- causal depthwise conv (width 4) + silu ----------
__global__ void __launch_bounds__(256)
conv_kernel(const u16* __restrict__ xz, const float* __restrict__ cw,
            const float* __restrict__ cb, u16* __restrict__ xc)
{
  const int d = blockIdx.x * 256 + threadIdx.x;   // 0..1535
  const int bl = blockIdx.y;                      // 0..8191
  const int l = bl & (SEQL - 1);
  const float w0 = cw[d * 4 + 0], w1 = cw[d * 4 + 1], w2 = cw[d * 4 + 2], w3 = cw[d * 4 + 3];
  const u16* xp = xz + (size_t)bl * 3072 + d;
  float acc = cb[d];
  acc += w3 * b2f(xp[0]);
  if (l >= 1) acc += w2 * b2f(xp[-3072]);
  if (l >= 2) acc += w1 * b2f(xp[-2 * 3072]);
  if (l >= 3) acc += w0 * b2f(xp[-3 * 3072]);
  const float sv = acc / (1.f + __expf(-acc));
  xc[(size_t)bl * 1536 + d] = f2b(sv);
}

// ---------- chunked selective scan ----------
// pass 1: per (b,chunk,d): run h from 0 over TCH steps; store end-state + sum(dt).
__global__ void __launch_bounds__(256)
scan1_kernel(const u16* __restrict__ xc, const u16* __restrict__ dt,
             const float* __restrict__ proj, const float* __restrict__ Alog,
             float* __restrict__ cstate, float* __restrict__ csum)
{
  __shared__ float sB[TCH][16];
  const int d = blockIdx.x * 256 + threadIdx.x;   // 0..1535
  const int c = blockIdx.y, b = blockIdx.z;
  const size_t rowbase = (size_t)b * SEQL + c * TCH;
  float A2[16];
#pragma unroll
  for (int s = 0; s < 16; ++s)
    A2[s] = -expf(Alog[d * 16 + s]) * 1.44269504088896340736f;
  for (int idx = threadIdx.x; idx < TCH * 16; idx += 256) {
    const int j = idx >> 4, s = idx & 15;
    sB[j][s] = proj[(rowbase + j) * 128 + 48 + s];
  }
  __syncthreads();
  float h[16] = {};
  float sumdt = 0.f;
  for (int t = 0; t < TCH; ++t) {
    const size_t r = rowbase + t;
    const float dtv = b2f(dt[r * 1536 + d]);
    const float xv  = b2f(xc[r * 1536 + d]);
    sumdt += dtv;
    const float w = dtv * xv;
#pragma unroll
    for (int s = 0; s < 16; ++s)
      h[s] = exp2f(dtv * A2[s]) * h[s] + w * sB[t][s];
  }
#pragma unroll
  for (int s = 0; s < 16; ++s)
    cstate[(((size_t)b * NC + c) * 16 + s) * 1536 + d] = h[s];
  csum[((size_t)b * NC + c) * 1536 + d] = sumdt;
}

// pass 2: per (b,d,s): sequential combine across chunks, in place:
// init_c = H;  H = exp(A*sumdt_c)*H + end_c
__global__ void __launch_bounds__(256)
scan2_kernel(const float* __restrict__ Alog, float* __restrict__ cstate,
             const float* __restrict__ csum)
{
  const int d = blockIdx.x * 256 + threadIdx.x;
  const int s = blockIdx.y, b = blockIdx.z;
  const float A2 = -expf(Alog[d * 16 + s]) * 1.44269504088896340736f;
  float H = 0.f;
  for (int c = 0; c < NC; ++c) {
    float* p = cstate + (((size_t)b * NC + c) * 16 + s) * 1536 + d;
    const float e = exp2f(A2 * csum[((size_t)b * NC + c) * 1536 + d]);
    const float endv = *p;
    *p = H;
    H = e * H + endv;
  }
}

// pass 3: per (b,chunk,d): re-run from corrected init, emit y = (h.C + x*D)*silu(z)
__global__ void __launch_bounds__(256)
scan3_kernel(const u16* __restrict__ xc, const u16* __restrict__ dt,
             const float* __restrict__ proj, const u16* __restrict__ xz,
             const float* __restrict__ Alog, const float* __restrict__ Dp,
             const float* __restrict__ cstate, u16* __restrict__ ys)
{
  __shared__ float sB[TCH][16], sC[TCH][16];
  const int d = blockIdx.x * 256 + threadIdx.x;
  const int c = blockIdx.y, b = blockIdx.z;
  const size_t rowbase = (size_t)b * SEQL + c * TCH;
  float A2[16];
#pragma unroll
  for (int s = 0; s < 16; ++s)
    A2[s] = -expf(Alog[d * 16 + s]) * 1.44269504088896340736f;
  const float Dv = Dp[d];
  for (int idx = threadIdx.x; idx < TCH * 16; idx += 256) {
    const int j = idx >> 4, s = idx & 15;
    sB[j][s] = proj[(rowbase + j) * 128 + 48 + s];
    sC[j][s] = proj[(rowbase + j) * 128 + 64 + s];
  }
  __syncthreads();
  float h[16];
#pragma unroll
  for (int s = 0; s < 16; ++s)
    h[s] = cstate[(((size_t)b * NC + c) * 16 + s) * 1536 + d];
  for (int t = 0; t < TCH; ++t) {
    const size_t r = rowbase + t;
    const float dtv = b2f(dt[r * 1536 + d]);
    const float xv  = b2f(xc[r * 1536 + d]);
    const float w = dtv * xv;
    float y = xv * Dv;
#pragma unroll
    for (int s = 0; s < 16; ++s) {
      h[s] = exp2f(dtv * A2[s]) * h[s] + w * sB[t][s];
      y += h[s] * sC[t][s];
    }
    const float zv = b2f(xz[r * 3072 + 1536 + d]);
    y *= zv / (1.f + __expf(-zv));
    ys[r * 1536 + d] = f2b(y);
  }
}

// ---------- weight conversion ----------
__global__ void __launch_bounds__(256)
cvt_kernel(const float* __restrict__ src, u16* __restrict__ dst, int n)
{
  const int i = blockIdx.x * 256 + threadIdx.x;
  if (i < n) dst[i] = f2b(src[i]);
}
__global__ void __launch_bounds__(256)
cvt_pad_xproj(const float* __restrict__ src, u16* __restrict__ dst)
{
  // src [80][1536] -> dst [128][1536] (rows >=80 zero)
  const int c = blockIdx.x * 256 + threadIdx.x;
  const int r = blockIdx.y;
  dst[(size_t)r * 1536 + c] = (r < 80) ? f2b(src[(size_t)r * 1536 + c]) : (u16)0;
}
__global__ void __launch_bounds__(64)
cvt_pad_dtp(const float* __restrict__ src, u16* __restrict__ dst)
{
  // src [1536][48] -> dst [1536][64] (cols >=48 zero)
  const int c = threadIdx.x, r = blockIdx.x;
  dst[(size_t)r * 64 + c] = (c < 48) ? f2b(src[(size_t)r * 48 + c]) : (u16)0;
}

extern "C" void kernel_launch(void* const* d_in, const int* in_sizes, int n_in,
                              void* d_out, int out_size, void* d_ws, size_t ws_size,
                              hipStream_t stream)
{
  (void)in_sizes; (void)n_in; (void)out_size; (void)ws_size;
  const int*   x      = (const int*)d_in[0];
  const float* tok    = (const float*)d_in[1];
  const float* pos    = (const float*)d_in[2];
  const float* ln1g   = (const float*)d_in[3];
  const float* ln1b   = (const float*)d_in[4];
  const float* in_w   = (const float*)d_in[5];
  const float* conv_w = (const float*)d_in[6];
  const float* conv_b = (const float*)d_in[7];
  const float* xprojw = (const float*)d_in[8];
  const float* dtpw   = (const float*)d_in[9];
  const float* dtpb   = (const float*)d_in[10];
  const float* Alog   = (const float*)d_in[11];
  const float* Dp     = (const float*)d_in[12];
  const float* out_w  = (const float*)d_in[13];
  const float* ln2g   = (const float*)d_in[14];
  const float* ln2b   = (const float*)d_in[15];
  const float* w1     = (const float*)d_in[16];
  const float* b1     = (const float*)d_in[17];
  const float* w2     = (const float*)d_in[18];
  const float* b2     = (const float*)d_in[19];
  float* h = (float*)d_out;

  char* ws = (char*)d_ws;
  size_t off = 0;
  auto alloc = [&](size_t bytes) -> void* {
    void* p = ws + off;
    off += (bytes + 255) & ~(size_t)255;
    return p;
  };
  u16* wbIn  = (u16*)alloc((size_t)NL * 3072 * 768 * 2);
  u16* wbOut = (u16*)alloc((size_t)NL * 768 * 1536 * 2);
  u16* wbW1  = (u16*)alloc((size_t)NL * 3072 * 768 * 2);
  u16* wbW2  = (u16*)alloc((size_t)NL * 768 * 3072 * 2);
  u16* wbXp  = (u16*)alloc((size_t)NL * 128 * 1536 * 2);
  u16* wbDtp = (u16*)alloc((size_t)NL * 1536 * 64 * 2);
  u16* aBf   = (u16*)alloc((size_t)MROWS * 768 * 2);
  u16* xzBf  = (u16*)alloc((size_t)MROWS * 3072 * 2);
  u16* xcBf  = (u16*)alloc((size_t)MROWS * 1536 * 2);
  float* projF = (float*)alloc((size_t)MROWS * 128 * 4);
  u16* dtrBf = (u16*)alloc((size_t)MROWS * 64 * 2);
  u16* dtBf  = (u16*)alloc((size_t)MROWS * 1536 * 2);
  u16* ysBf  = (u16*)alloc((size_t)MROWS * 1536 * 2);
  u16* f1Bf  = xzBf;  // alias: z consumed by scan before MLP writes f1
  // scan chunk buffers alias memory that is dead during the scan phase:
  // aBf (LN output, consumed by in_proj GEMM) and dtrBf (consumed by dt GEMM).
  float* cstate = (float*)aBf;    // [B][NC][16][1536] fp32 = 12.58 MB == sizeof(aBf)
  float* csum   = (float*)dtrBf;  // [B][NC][1536]     fp32 = 0.79 MB  <= sizeof(dtrBf)

  // convert weights to bf16 (every call; deterministic)
  { int n = NL * 3072 * 768; cvt_kernel<<<(n + 255) / 256, 256, 0, stream>>>(in_w, wbIn, n); }
  { int n = NL * 768 * 1536; cvt_kernel<<<(n + 255) / 256, 256, 0, stream>>>(out_w, wbOut, n); }
  { int n = NL * 3072 * 768; cvt_kernel<<<(n + 255) / 256, 256, 0, stream>>>(w1, wbW1, n); }
  { int n = NL * 768 * 3072; cvt_kernel<<<(n + 255) / 256, 256, 0, stream>>>(w2, wbW2, n); }
  for (int i = 0; i < NL; ++i) {
    cvt_pad_xproj<<<dim3(6, 128), 256, 0, stream>>>(xprojw + (size_t)i * 80 * 1536,
                                                    wbXp + (size_t)i * 128 * 1536);
    cvt_pad_dtp<<<1536, 64, 0, stream>>>(dtpw + (size_t)i * 1536 * 48,
                                         wbDtp + (size_t)i * 1536 * 64);
  }

  embed_kernel<<<MROWS, 256, 0, stream>>>(x, tok, pos, h);

  for (int i = 0; i < NL; ++i) {
    ln_kernel<<<MROWS, 256, 0, stream>>>(h, ln1g + i * 768, ln1b + i * 768, aBf);
    gemm_bt<EPI_BF16><<<dim3(24, 64), 256, 0, stream>>>(
        aBf, wbIn + (size_t)i * 3072 * 768, 768, 3072, nullptr, xzBf, nullptr);
    conv_kernel<<<dim3(6, MROWS), 256, 0, stream>>>(
        xzBf, conv_w + (size_t)i * 1536 * 4, conv_b + (size_t)i * 1536, xcBf);
    gemm_bt<EPI_PROJ><<<dim3(1, 64), 256, 0, stream>>>(
        xcBf, wbXp + (size_t)i * 128 * 1536, 1536, 128, projF, dtrBf, nullptr);
    gemm_bt<EPI_SOFTPLUS><<<dim3(12, 64), 256, 0, stream>>>(
        dtrBf, wbDtp + (size_t)i * 1536 * 64, 64, 1536, nullptr, dtBf, dtpb + i * 1536);
    scan1_kernel<<<dim3(6, NC, 4), 256, 0, stream>>>(
        xcBf, dtBf, projF, Alog + (size_t)i * 1536 * 16, cstate, csum);
    scan2_kernel<<<dim3(6, 16, 4), 256, 0, stream>>>(
        Alog + (size_t)i * 1536 * 16, cstate, csum);
    scan3_kernel<<<dim3(6, NC, 4), 256, 0, stream>>>(
        xcBf, dtBf, projF, xzBf, Alog + (size_t)i * 1536 * 16, Dp + i * 1536,
        cstate, ysBf);
    gemm_bt<EPI_ADDF32><<<dim3(6, 64), 256, 0, stream>>>(
        ysBf, wbOut + (size_t)i * 768 * 1536, 1536, 768, h, nullptr, nullptr);
    ln_kernel<<<MROWS, 256, 0, stream>>>(h, ln2g + i * 768, ln2b + i * 768, aBf);
    gemm_bt<EPI_BIASRELU><<<dim3(24, 64), 256, 0, stream>>>(
        aBf, wbW1 + (size_t)i * 3072 * 768, 768, 3072, nullptr, f1Bf, b1 + i * 3072);
    gemm_bt<EPI_ADDBIAS><<<dim3(6, 64), 256, 0, stream>>>(
        f1Bf, wbW2 + (size_t)i * 768 * 3072, 3072, 768, h, nullptr, b2 + i * 768);
  }
}